// Round 1
// baseline (84.489 us; speedup 1.0000x reference)
//
#include <hip/hip_runtime.h>

// Gaussian RBF soft-histogram:
//   out[b,o,p] = sum_j exp( -(x[b,j,p] - c[o,j])^2 / (2*w[o,j]^2) )
// x: [B=8, CIN=8, HW=65536] f32; c,w: [COUT=16, CIN=8]; out: [B=8, COUT=16, HW] f32
//
// R3: constants out of LDS into SGPRs. rocprof showed rbf_hist_kernel absent
// from the top-5 dispatches (all 43us 256MiB ws poison-fills at HBM peak), so
// the kernel itself is <43us and a big share of dur_us is harness resets.
// Kernel-side, the largest non-memory pipe was LDS: 128 ds_read_b64/thread
// (6.8us chip-wide on the shared per-CU LDS pipe) + lgkm waits interleaved
// with the math. This version: a 1-block prep kernel bakes (c, -log2e/(2w^2))
// into a 1KB table in d_ws; the main kernel reads it at compile-time-constant
// wave-uniform offsets via __restrict__ -> s_load into SGPRs (no LDS, no lgkm
// in the hot loop, SGPR operands are free). 2 px/thread float2 loads/stores
// (8B/lane coalescing sweet spot), 1024 blocks = 4 waves/SIMD,
// __launch_bounds__(256,4) caps VGPR at 128 (kernel needs ~40, no spill).
// Direct (x-c)^2 form kept for numerical safety vs tiny widths.

constexpr int CIN   = 8;
constexpr int COUT  = 16;
constexpr int HW    = 256 * 256;   // 65536
constexpr int BATCH = 8;
constexpr int PXT   = 2;           // pixels per thread

__global__ void rbf_prep_kernel(const float* __restrict__ centers,
                                const float* __restrict__ widths,
                                float2* __restrict__ tab)
{
    const int i = threadIdx.x;
    if (i < COUT * CIN) {
        const float w = widths[i];
        const float negk = -1.4426950408889634f / (2.0f * w * w);  // -log2(e)/(2w^2)
        tab[i] = make_float2(centers[i], negk);
    }
}

__global__ __launch_bounds__(256, 4) void rbf_hist_kernel(
    const float* __restrict__ x,
    const float2* __restrict__ tab,
    float* __restrict__ out)
{
    const int t = blockIdx.x * 256 + threadIdx.x;   // 0 .. B*HW/PXT - 1
    const int b = t >> 15;                          // t / (HW/PXT), HW/PXT = 32768
    const int p = (t & (HW / PXT - 1)) * PXT;       // pixel pair base

    // Load this thread's 2 pixels x 8 channels (x read exactly once from HBM,
    // 8B/lane float2 loads, 512B per wave instruction).
    const float* __restrict__ xb = x + (size_t)(b * CIN) * HW + p;
    float2 xr[CIN];
#pragma unroll
    for (int j = 0; j < CIN; ++j) {
        xr[j] = *reinterpret_cast<const float2*>(xb + (size_t)j * HW);
    }

    float* __restrict__ ob = out + (size_t)(b * COUT) * HW + p;

#pragma unroll 4
    for (int o = 0; o < COUT; ++o) {
        float ax = 0.f, ay = 0.f;
#pragma unroll
        for (int j = 0; j < CIN; ++j) {
            // Wave-uniform, compile-time-constant offset from a __restrict__
            // kernel arg -> scalar load (s_load_dwordx*), constants live in
            // SGPRs: zero LDS traffic, zero lgkmcnt in the math loop.
            const float2 cn = tab[o * CIN + j];
            const float d0 = xr[j].x - cn.x;
            const float d1 = xr[j].y - cn.x;
            ax += __builtin_amdgcn_exp2f((cn.y * d0) * d0);
            ay += __builtin_amdgcn_exp2f((cn.y * d1) * d1);
        }
        *reinterpret_cast<float2*>(ob + (size_t)o * HW) = make_float2(ax, ay);
    }
}

extern "C" void kernel_launch(void* const* d_in, const int* in_sizes, int n_in,
                              void* d_out, int out_size, void* d_ws, size_t ws_size,
                              hipStream_t stream) {
    const float* x       = (const float*)d_in[0];
    const float* centers = (const float*)d_in[1];
    const float* widths  = (const float*)d_in[2];
    float* out           = (float*)d_out;
    float2* tab          = (float2*)d_ws;          // 128 * 8B = 1KB of workspace

    rbf_prep_kernel<<<1, 128, 0, stream>>>(centers, widths, tab);

    const int total_threads = BATCH * HW / PXT;    // 262144
    const int block = 256;
    const int grid  = total_threads / block;       // 1024 blocks
    rbf_hist_kernel<<<grid, block, 0, stream>>>(x, tab, out);
}

// Round 2
// 83.424 us; speedup vs baseline: 1.0128x; 1.0128x over previous
//
#include <hip/hip_runtime.h>

// Gaussian RBF soft-histogram:
//   out[b,o,p] = sum_j exp( -(x[b,j,p] - c[o,j])^2 / (2*w[o,j]^2) )
// x: [B=8, CIN=8, HW=65536] f32; c,w: [COUT=16, CIN=8]; out: [B=8, COUT=16, HW] f32
//
// R4: merge best-of-R2/R3. Dispatch-ID analysis showed the timed iteration is
// 6 dispatches (R2) vs 7 (R3) -> R3's prep kernel added ~2us of serialized
// launch overhead, explaining the 82.9->84.5 regression; its SGPR-constant win
// was smaller than one launch. This version: single kernel again (LDS
// constants, one copy per block, conflict-free broadcast reads hoisted per-o),
// keeping R3's 2 px/thread float2 loads/stores (half the instruction count
// per element, 512B/wave per stream, packed-f32 VALU opportunity on the
// pixel pairs). __launch_bounds__(256,6): VGPR cap 84 (kernel ~60, no
// spill), 6 waves/SIMD -- occupancy beyond ~4 is already insensitive
// (R1 2w/SIMD vs R2 8w/SIMD differed by 1.4us).
// Direct (x-c)^2 form kept: expanded-quadratic FMA form risks cancellation
// with tiny widths (negk up to ~1e4-1e5 for |w|~1e-2).
//
// Budget: ~70us/iter is harness resets (256MiB ws poison-fill at 76% HBM peak
// + out poison + verify traffic); kernel residual ~12-15us vs 8.1us memory
// floor (50.3MB @ 6.3TB/s). If this round doesn't beat 82.3, harness floor is
// confirmed -> roofline.

constexpr int CIN   = 8;
constexpr int COUT  = 16;
constexpr int HW    = 256 * 256;   // 65536
constexpr int BATCH = 8;
constexpr int PXT   = 2;           // pixels per thread

__global__ __launch_bounds__(256, 6) void rbf_hist_kernel(
    const float* __restrict__ x,
    const float* __restrict__ centers,
    const float* __restrict__ widths,
    float* __restrict__ out)
{
    __shared__ float2 s_cn[COUT * CIN];   // (center, negk), negk = -log2e/(2 w^2)

    const int tid = threadIdx.x;
    if (tid < COUT * CIN) {
        const float w = widths[tid];
        const float negk = -1.4426950408889634f / (2.0f * w * w);
        s_cn[tid] = make_float2(centers[tid], negk);
    }
    __syncthreads();

    const int t = blockIdx.x * 256 + tid;           // 0 .. B*HW/PXT - 1
    const int b = t >> 15;                          // t / (HW/PXT), HW/PXT = 32768
    const int p = (t & (HW / PXT - 1)) * PXT;       // pixel-pair base

    // Load this thread's 2 pixels x 8 channels (x read exactly once from HBM,
    // 8B/lane float2 loads, 512B per wave per stream).
    const float* __restrict__ xb = x + (size_t)(b * CIN) * HW + p;
    float2 xr[CIN];
#pragma unroll
    for (int j = 0; j < CIN; ++j) {
        xr[j] = *reinterpret_cast<const float2*>(xb + (size_t)j * HW);
    }

    float* __restrict__ ob = out + (size_t)(b * COUT) * HW + p;

#pragma unroll 2
    for (int o = 0; o < COUT; ++o) {
        // Hoist this o's 8 (center, negk) pairs: wave-uniform LDS broadcast,
        // conflict-free, compiler pairs into ds_read2_b64.
        float2 cn[CIN];
#pragma unroll
        for (int j = 0; j < CIN; ++j) {
            cn[j] = s_cn[o * CIN + j];
        }
        float ax = 0.f, ay = 0.f;
#pragma unroll
        for (int j = 0; j < CIN; ++j) {
            const float d0 = xr[j].x - cn[j].x;
            const float d1 = xr[j].y - cn[j].x;
            ax += __builtin_amdgcn_exp2f((cn[j].y * d0) * d0);
            ay += __builtin_amdgcn_exp2f((cn[j].y * d1) * d1);
        }
        *reinterpret_cast<float2*>(ob + (size_t)o * HW) = make_float2(ax, ay);
    }
}

extern "C" void kernel_launch(void* const* d_in, const int* in_sizes, int n_in,
                              void* d_out, int out_size, void* d_ws, size_t ws_size,
                              hipStream_t stream) {
    const float* x       = (const float*)d_in[0];
    const float* centers = (const float*)d_in[1];
    const float* widths  = (const float*)d_in[2];
    float* out           = (float*)d_out;

    const int total_threads = BATCH * HW / PXT;    // 262144
    const int block = 256;
    const int grid  = total_threads / block;       // 1024 blocks

    rbf_hist_kernel<<<grid, block, 0, stream>>>(x, centers, widths, out);
}